// Round 13
// baseline (132.916 us; speedup 1.0000x reference)
//
#include <hip/hip_runtime.h>

// Fused LSTM B=16384, T=60, IN=1, H=50, OUT=1 — R10 base + trans-free math.
// 512 blocks x 256 thr (4 waves, 2 blocks/CU). Dual 16-batch groups/block.
// R4-R12 ledger: wall ~4000 cyc/step invariant to occupancy/ILP/balance/DS;
// fit wall ~= 45 cyc x (trans ops/SIMD/step) -> transcendental pipe IS the
// wall. This round: v_exp_f32 -> 9-op FMA-only poly exp2 (rndne reduce,
// Taylor-4, exponent via (n+127)<<23 bitcast; rel err 4e-5); rcps batched
// across groups (Montgomery) -> trans/wave-step 56 -> 8. Plus R11's tile
// balance {4,3,3,3} rotated by hv=bid&3 (SIMD pace 8->7 tau).
// unit u = 4T+du, identity k-map, bias k=62, x k=63; H fp16 [cl][64]
// chunk-XOR swizzled dbuf/grp; fp16(hi) A-frags in VGPRs; c fp32.

namespace {
constexpr int TS = 60;

typedef _Float16 half8 __attribute__((ext_vector_type(8)));
typedef _Float16 half2v __attribute__((ext_vector_type(2)));
typedef float f32x4 __attribute__((ext_vector_type(4)));

__device__ __forceinline__ float frcp(float x) { return __builtin_amdgcn_rcpf(x); }

// FMA-only 2^x: rndne reduce, Taylor-4 on [-0.5,0.5] (rel err <= 4.2e-5),
// scale via exponent-bit construction. Valid for x in ~[-126, 127].
__device__ __forceinline__ float pexp2(float x) {
  const float t = __builtin_rintf(x);
  const float f = x - t;
  float p = 9.6181291e-3f;                 // ln2^4/24
  p = fmaf(p, f, 5.5504109e-2f);           // ln2^3/6
  p = fmaf(p, f, 2.4022651e-1f);           // ln2^2/2
  p = fmaf(p, f, 6.9314718e-1f);           // ln2
  p = fmaf(p, f, 1.0f);
  const int n = (int)t;
  const float s = __builtin_bit_cast(float, (n + 127) << 23);
  return p * s;
}
__device__ __forceinline__ f32x4 mfma16(half8 a, half8 b, f32x4 c) {
  return __builtin_amdgcn_mfma_f32_16x16x32_f16(a, b, c, 0, 0, 0);
}
}  // namespace

__global__ __launch_bounds__(256, 2) void lstm_poly(
    const float* __restrict__ x,      // [B][60]
    const float* __restrict__ w_ih,   // [200]
    const float* __restrict__ w_hh,   // [200][50]
    const float* __restrict__ b_ih,   // [200]
    const float* __restrict__ b_hh,   // [200]
    const float* __restrict__ w_lin,  // [3000]
    const float* __restrict__ b_lin,  // [1]
    float* __restrict__ out)          // [B]
{
  __shared__ __align__(16) _Float16 Hs[2][2][16 * 64];  // [grp][buf] 8 KB
  __shared__ float WL[TS * 64];   // 15.36 KB [t][u], 0-padded
  __shared__ float XL[TS * 32];   // 7.68 KB [t][b]
  __shared__ float OB[4][2][16];  // 512 B

  const int tid = threadIdx.x;
  const int lane = tid & 63;
  const int wv = tid >> 6;   // 0..3
  const int g = lane >> 4;   // B k-owner / D row-block (du)
  const int cl = lane & 15;  // batch-in-group; A/B/D column
  const int s8 = cl & 7;
  const int bid = blockIdx.x;
  const long bbase = (long)bid * 32;

  // balanced tiles {4,3,3,3}, heavy wave rotated per block
  const int hv = bid & 3;
  const int ntile = 3 + (wv == hv);
  const int tbase = 3 * wv + (wv > hv ? 1 : 0);

  // ---- stage XL[t][b] ----
  for (int i = tid; i < TS * 32; i += 256) {
    const int b = i / TS, t = i - b * TS;
    XL[t * 32 + b] = x[bbase * TS + i];
  }
  // ---- stage WL[t][u] ----
  for (int i = tid; i < TS * 64; i += 256) {
    const int t = i >> 6, u = i & 63;
    WL[i] = (u < 50) ? w_lin[t * 50 + u] : 0.0f;
  }
  // ---- zero all H buffers ----
  for (int i = tid; i < 2048; i += 256) ((unsigned*)Hs)[i] = 0u;

  // ---- gather this wave's A-fragments (fp32 -> fp16), once ----
  half8 A[4][2];
  {
    const int gate = cl & 3, du = cl >> 2;
#pragma unroll
    for (int tau = 0; tau < 4; ++tau) {
      const int T = tbase + tau;
      const int uA = 4 * T + du;
      const int orig = gate * 50 + uA;
      const bool valid = (tau < ntile) && (uA < 50);
#pragma unroll
      for (int kc = 0; kc < 2; ++kc) {
        half8 fr;
#pragma unroll
        for (int e = 0; e < 8; ++e) {
          const int k = kc * 32 + 8 * g + e;
          float v = 0.0f;
          if (valid) {
            if (k < 50) v = w_hh[orig * 50 + k];
            else if (k == 62) v = b_ih[orig] + b_hh[orig];
            else if (k == 63) v = w_ih[orig];
          }
          fr[e] = (_Float16)v;
        }
        A[tau][kc] = fr;
      }
    }
  }
  __syncthreads();

  // ---- specials in buf0 (both groups): k=62 -> 1.0, k=63 -> x_0 ----
  if (wv == 3 && g == 3) {
#pragma unroll
    for (int grp = 0; grp < 2; ++grp) {
      const half2v sp = {(_Float16)1.0f, (_Float16)XL[grp * 16 + cl]};
      *(half2v*)&Hs[grp][0][cl * 64 + ((7 ^ s8) << 3) + 6] = sp;
    }
  }
  __syncthreads();

  const int rh0 = cl * 64 + ((g ^ s8) << 3);
  const int rh1 = cl * 64 + (((4 | g) ^ s8) << 3);

  float c0[4] = {0.f, 0.f, 0.f, 0.f};
  float c1[4] = {0.f, 0.f, 0.f, 0.f};
  float oacc0 = 0.f, oacc1 = 0.f;

  constexpr float L1 = 1.4426950408889634f;  // log2(e)
  constexpr float L2 = 2.8853900817779268f;  // 2*log2(e)

#pragma unroll 1
  for (int t = 0; t < TS; ++t) {
    const int p = t & 1;
    const _Float16* HR0 = &Hs[0][p][0];
    const _Float16* HR1 = &Hs[1][p][0];
    _Float16* HN0 = &Hs[0][p ^ 1][0];
    _Float16* HN1 = &Hs[1][p ^ 1][0];
    const half8 B0a = *(const half8*)&HR0[rh0];
    const half8 B1a = *(const half8*)&HR0[rh1];
    const half8 B0b = *(const half8*)&HR1[rh0];
    const half8 B1b = *(const half8*)&HR1[rh1];

    f32x4 da[4], db[4];
#pragma unroll
    for (int tau = 0; tau < 4; ++tau) {
      if (tau < ntile) {
        f32x4 z = {0.f, 0.f, 0.f, 0.f};
        da[tau] = mfma16(A[tau][1], B1a, mfma16(A[tau][0], B0a, z));
        db[tau] = mfma16(A[tau][1], B1b, mfma16(A[tau][0], B0b, z));
      }
    }

#pragma unroll
    for (int tau = 0; tau < 4; ++tau) {
      if (tau < ntile) {
        const int u = 4 * (tbase + tau) + g;
        const float wlv = WL[t * 64 + u];
        const int widx = cl * 64 + (((u >> 3) ^ s8) << 3) + (u & 7);
        // ---- gates, grp 0 ----
        const float E1a = pexp2(-L1 * da[tau][0]);
        const float E2a = pexp2(-L1 * da[tau][1]);
        const float E3a = pexp2(-L1 * da[tau][3]);
        const float E4a = pexp2(L2 * da[tau][2]);
        const float P1a = 1.0f + E1a, P2a = 1.0f + E2a;
        const float P3a = 1.0f + E3a, P4a = 1.0f + E4a;
        const float p12a = P1a * P2a, p34a = P3a * P4a;
        const float pra = p12a * p34a;
        // ---- gates, grp 1 ----
        const float E1b = pexp2(-L1 * db[tau][0]);
        const float E2b = pexp2(-L1 * db[tau][1]);
        const float E3b = pexp2(-L1 * db[tau][3]);
        const float E4b = pexp2(L2 * db[tau][2]);
        const float P1b = 1.0f + E1b, P2b = 1.0f + E2b;
        const float P3b = 1.0f + E3b, P4b = 1.0f + E4b;
        const float p12b = P1b * P2b, p34b = P3b * P4b;
        const float prb = p12b * p34b;
        // ---- one rcp for both groups (Montgomery) ----
        const float R = frcp(pra * prb);
        const float ra = R * prb, rb = R * pra;
        // ---- grp 0 c/h ----
        const float r12a = ra * p34a, r34a = ra * p12a;
        const float sia = r12a * P2a, sfa = r12a * P1a, soa = r34a * P4a;
        const float tga = fmaf(-2.0f, r34a * P3a, 1.0f);
        const float cna = fmaf(sfa, c0[tau], sia * tga);
        c0[tau] = cna;
        // ---- grp 1 c/h ----
        const float r12b = rb * p34b, r34b = rb * p12b;
        const float sib = r12b * P2b, sfb = r12b * P1b, sob = r34b * P4b;
        const float tgb = fmaf(-2.0f, r34b * P3b, 1.0f);
        const float cnb = fmaf(sfb, c1[tau], sib * tgb);
        c1[tau] = cnb;
        // ---- tanh(cn), one rcp for both groups; clamp arg (|cn| can grow) ----
        const float aca = fminf(fmaxf(L2 * cna, -14.5f), 14.5f);
        const float acb = fminf(fmaxf(L2 * cnb, -14.5f), 14.5f);
        const float Pca = 1.0f + pexp2(aca);
        const float Pcb = 1.0f + pexp2(acb);
        const float Rc = frcp(Pca * Pcb);
        const float tca = fmaf(-2.0f, Rc * Pcb, 1.0f);
        const float tcb = fmaf(-2.0f, Rc * Pca, 1.0f);
        const float hna = soa * tca;
        const float hnb = sob * tcb;
        oacc0 = fmaf(hna, wlv, oacc0);
        oacc1 = fmaf(hnb, wlv, oacc1);
        HN0[widx] = (_Float16)hna;
        HN1[widx] = (_Float16)hnb;
      }
    }
    if (wv == 3 && g == 3) {  // specials for next step
      const int tn = (t + 1 < TS) ? (t + 1) : (TS - 1);
      const half2v spa = {(_Float16)1.0f, (_Float16)XL[tn * 32 + cl]};
      const half2v spb = {(_Float16)1.0f, (_Float16)XL[tn * 32 + 16 + cl]};
      *(half2v*)&HN0[cl * 64 + ((7 ^ s8) << 3) + 6] = spa;
      *(half2v*)&HN1[cl * 64 + ((7 ^ s8) << 3) + 6] = spb;
    }
    __syncthreads();
  }

  // ---- reduce over g (shfl), then over waves (LDS) ----
  oacc0 += __shfl_xor(oacc0, 32);
  oacc0 += __shfl_xor(oacc0, 16);
  oacc1 += __shfl_xor(oacc1, 32);
  oacc1 += __shfl_xor(oacc1, 16);
  if (lane < 16) {
    OB[wv][0][cl] = oacc0;
    OB[wv][1][cl] = oacc1;
  }
  __syncthreads();
  if (tid < 32) {
    const int grp = tid >> 4, b = tid & 15;
    float s = b_lin[0];
#pragma unroll
    for (int q = 0; q < 4; ++q) s += OB[q][grp][b];
    out[bbase + grp * 16 + b] = s;
  }
}

extern "C" void kernel_launch(void* const* d_in, const int* in_sizes, int n_in,
                              void* d_out, int out_size, void* d_ws, size_t ws_size,
                              hipStream_t stream) {
  const float* x     = (const float*)d_in[0];
  const float* w_ih  = (const float*)d_in[1];
  const float* w_hh  = (const float*)d_in[2];
  const float* b_ih  = (const float*)d_in[3];
  const float* b_hh  = (const float*)d_in[4];
  const float* w_lin = (const float*)d_in[5];
  const float* b_lin = (const float*)d_in[6];
  float* out = (float*)d_out;

  dim3 grid(16384 / 32);  // 512 blocks -> 2 per CU
  dim3 block(256);
  lstm_poly<<<grid, block, 0, stream>>>(x, w_ih, w_hh, b_ih, b_hh, w_lin,
                                        b_lin, out);
}

// Round 14
// 93.094 us; speedup vs baseline: 1.4278x; 1.4278x over previous
//
#include <hip/hip_runtime.h>

// Fused LSTM B=16384, T=60, IN=1, H=50, OUT=1 — R10 (best, 91.4us) + block
// phase-stagger. R4-R13 ledger: wall/step ~4000 cyc/CU invariant to
// occupancy/chains/balance/DS; per-slot issue model fits R6/R10/R13
// (trans cheap, VALU 2cyc); R12(1blk/CU) == R10(2blk/CU) -> co-resident
// blocks contribute NO overlap = phase-locked convoy (identical code,
// simultaneous start, lock-step stalls). This round: odd blocks s_sleep
// ~2000cyc (half a step) once before the t-loop so the 2 blocks/CU
// interleave their stall phases. Everything else == R10 verbatim.

namespace {
constexpr int TS = 60;

typedef _Float16 half8 __attribute__((ext_vector_type(8)));
typedef _Float16 half2v __attribute__((ext_vector_type(2)));
typedef float f32x4 __attribute__((ext_vector_type(4)));

__device__ __forceinline__ float fexp2(float x) { return __builtin_amdgcn_exp2f(x); }
__device__ __forceinline__ float frcp(float x) { return __builtin_amdgcn_rcpf(x); }
__device__ __forceinline__ f32x4 mfma16(half8 a, half8 b, f32x4 c) {
  return __builtin_amdgcn_mfma_f32_16x16x32_f16(a, b, c, 0, 0, 0);
}
}  // namespace

__global__ __launch_bounds__(256, 2) void lstm_stag(
    const float* __restrict__ x,      // [B][60]
    const float* __restrict__ w_ih,   // [200]
    const float* __restrict__ w_hh,   // [200][50]
    const float* __restrict__ b_ih,   // [200]
    const float* __restrict__ b_hh,   // [200]
    const float* __restrict__ w_lin,  // [3000]
    const float* __restrict__ b_lin,  // [1]
    float* __restrict__ out)          // [B]
{
  __shared__ __align__(16) _Float16 Hs[2][2][16 * 64];  // [grp][buf] 8 KB
  __shared__ float WL[TS * 64];   // 15.36 KB [t][u], 0-padded
  __shared__ float XL[TS * 32];   // 7.68 KB [t][b]
  __shared__ float OB[4][2][16];  // 512 B

  const int tid = threadIdx.x;
  const int lane = tid & 63;
  const int wv = tid >> 6;   // 0..3
  const int g = lane >> 4;   // lane quad-group: B k-owner, D row-block (du)
  const int cl = lane & 15;  // batch-in-group; A/B/D column
  const int s8 = cl & 7;
  const long bbase = (long)blockIdx.x * 32;

  // ---- stage XL[t][b] ----
  for (int i = tid; i < TS * 32; i += 256) {
    const int b = i / TS, t = i - b * TS;
    XL[t * 32 + b] = x[bbase * TS + i];
  }
  // ---- stage WL[t][u] ----
  for (int i = tid; i < TS * 64; i += 256) {
    const int t = i >> 6, u = i & 63;
    WL[i] = (u < 50) ? w_lin[t * 50 + u] : 0.0f;
  }
  // ---- zero all H buffers (h0 = 0; pad k-slots stay 0 forever) ----
  for (int i = tid; i < 2048; i += 256) ((unsigned*)Hs)[i] = 0u;

  // ---- gather this wave's A-fragments (fp32 -> fp16), once ----
  half8 A[4][2];
  {
    const int gate = cl & 3, du = cl >> 2;
    const int ntile = (wv < 3) ? 4 : 1;
#pragma unroll
    for (int tau = 0; tau < 4; ++tau) {
      const int T = (wv < 3) ? (4 * wv + tau) : 12;
      const int uA = 4 * T + du;
      const int orig = gate * 50 + uA;
      const bool valid = (tau < ntile) && (uA < 50);
#pragma unroll
      for (int kc = 0; kc < 2; ++kc) {
        half8 fr;
#pragma unroll
        for (int e = 0; e < 8; ++e) {
          const int k = kc * 32 + 8 * g + e;
          float v = 0.0f;
          if (valid) {
            if (k < 50) v = w_hh[orig * 50 + k];
            else if (k == 62) v = b_ih[orig] + b_hh[orig];
            else if (k == 63) v = w_ih[orig];
          }
          fr[e] = (_Float16)v;
        }
        A[tau][kc] = fr;
      }
    }
  }
  __syncthreads();

  // ---- specials in buf0 (both groups): k=62 -> 1.0, k=63 -> x_0 ----
  if (wv == 3 && g == 3) {
#pragma unroll
    for (int grp = 0; grp < 2; ++grp) {
      const half2v sp = {(_Float16)1.0f, (_Float16)XL[grp * 16 + cl]};
      *(half2v*)&Hs[grp][0][cl * 64 + ((7 ^ s8) << 3) + 6] = sp;
    }
  }
  __syncthreads();

  // ---- PHASE STAGGER: odd blocks sleep ~2048 cyc (half a step) so the
  // two co-resident blocks per CU interleave stall phases instead of
  // convoying in lock-step. One-time cost, amortized over 60 steps.
  if (blockIdx.x & 1) {
    __builtin_amdgcn_s_sleep(15);  // ~960 cyc
    __builtin_amdgcn_s_sleep(15);
  }

  // B-frag read offsets (halves): kc0 -> chunk g, kc1 -> chunk 4+g
  const int rh0 = cl * 64 + ((g ^ s8) << 3);
  const int rh1 = cl * 64 + (((4 | g) ^ s8) << 3);

  float c[2][4] = {{0.f, 0.f, 0.f, 0.f}, {0.f, 0.f, 0.f, 0.f}};
  float oacc[2] = {0.f, 0.f};

  constexpr float L1 = 1.4426950408889634f;  // log2(e)
  constexpr float L2 = 2.8853900817779268f;  // 2*log2(e)

#define DO_TILES(NT, TBASE)                                                   \
  {                                                                           \
    f32x4 acc[2][NT];                                                         \
    _Pragma("unroll") for (int grp = 0; grp < 2; ++grp) {                     \
      _Pragma("unroll") for (int tau = 0; tau < NT; ++tau) {                  \
        f32x4 a = {0.f, 0.f, 0.f, 0.f};                                       \
        a = mfma16(A[tau][0], grp ? B0b : B0a, a);                            \
        a = mfma16(A[tau][1], grp ? B1b : B1a, a);                            \
        acc[grp][tau] = a;                                                    \
      }                                                                       \
    }                                                                         \
    _Pragma("unroll") for (int tau = 0; tau < NT; ++tau) {                    \
      const int u = 4 * (TBASE + tau) + g;                                    \
      const float wlv = WL[t * 64 + u];                                       \
      const int widx = cl * 64 + (((u >> 3) ^ s8) << 3) + (u & 7);            \
      _Pragma("unroll") for (int grp = 0; grp < 2; ++grp) {                   \
        const float E1 = fexp2(-L1 * acc[grp][tau][0]);                       \
        const float E2 = fexp2(-L1 * acc[grp][tau][1]);                       \
        const float E3 = fexp2(-L1 * acc[grp][tau][3]);                       \
        const float E4 = fexp2(L2 * acc[grp][tau][2]);                        \
        const float P1 = 1.0f + E1, P2 = 1.0f + E2;                           \
        const float P3 = 1.0f + E3, P4 = 1.0f + E4;                           \
        const float p12 = P1 * P2, p34 = P3 * P4;                             \
        const float r = frcp(p12 * p34);                                      \
        const float r12 = r * p34, r34 = r * p12;                             \
        const float si = r12 * P2, sf = r12 * P1, so = r34 * P4;              \
        const float tg = fmaf(-2.0f, r34 * P3, 1.0f);                         \
        const float cn = fmaf(sf, c[grp][tau], si * tg);                      \
        c[grp][tau] = cn;                                                     \
        const float Ec = fexp2(L2 * cn);                                      \
        const float tc = fmaf(-2.0f, frcp(1.0f + Ec), 1.0f);                  \
        const float hn = so * tc;                                             \
        oacc[grp] = fmaf(hn, wlv, oacc[grp]);                                 \
        (grp ? HN1 : HN0)[widx] = (_Float16)hn;                               \
      }                                                                       \
    }                                                                         \
  }

#pragma unroll 1
  for (int t = 0; t < TS; ++t) {
    const int p = t & 1;
    const _Float16* HR0 = &Hs[0][p][0];
    const _Float16* HR1 = &Hs[1][p][0];
    _Float16* HN0 = &Hs[0][p ^ 1][0];
    _Float16* HN1 = &Hs[1][p ^ 1][0];
    const half8 B0a = *(const half8*)&HR0[rh0];
    const half8 B1a = *(const half8*)&HR0[rh1];
    const half8 B0b = *(const half8*)&HR1[rh0];
    const half8 B1b = *(const half8*)&HR1[rh1];

    if (wv < 3) {
      const int tb = 4 * wv;
      DO_TILES(4, tb);
    } else {
      DO_TILES(1, 12);
      if (g == 3) {  // specials for next step: k=62 -> 1.0, k=63 -> x_{t+1}
        const int tn = (t + 1 < TS) ? (t + 1) : (TS - 1);
        const half2v spa = {(_Float16)1.0f, (_Float16)XL[tn * 32 + cl]};
        const half2v spb = {(_Float16)1.0f, (_Float16)XL[tn * 32 + 16 + cl]};
        *(half2v*)&HN0[cl * 64 + ((7 ^ s8) << 3) + 6] = spa;
        *(half2v*)&HN1[cl * 64 + ((7 ^ s8) << 3) + 6] = spb;
      }
    }
    __syncthreads();
  }
#undef DO_TILES

  // ---- reduce over g (shfl), then over waves (LDS) ----
  oacc[0] += __shfl_xor(oacc[0], 32);
  oacc[0] += __shfl_xor(oacc[0], 16);
  oacc[1] += __shfl_xor(oacc[1], 32);
  oacc[1] += __shfl_xor(oacc[1], 16);
  if (lane < 16) {
    OB[wv][0][cl] = oacc[0];
    OB[wv][1][cl] = oacc[1];
  }
  __syncthreads();
  if (tid < 32) {
    const int grp = tid >> 4, b = tid & 15;
    float s = b_lin[0];
#pragma unroll
    for (int q = 0; q < 4; ++q) s += OB[q][grp][b];
    out[bbase + grp * 16 + b] = s;
  }
}

extern "C" void kernel_launch(void* const* d_in, const int* in_sizes, int n_in,
                              void* d_out, int out_size, void* d_ws, size_t ws_size,
                              hipStream_t stream) {
  const float* x     = (const float*)d_in[0];
  const float* w_ih  = (const float*)d_in[1];
  const float* w_hh  = (const float*)d_in[2];
  const float* b_ih  = (const float*)d_in[3];
  const float* b_hh  = (const float*)d_in[4];
  const float* w_lin = (const float*)d_in[5];
  const float* b_lin = (const float*)d_in[6];
  float* out = (float*)d_out;

  dim3 grid(16384 / 32);  // 512 blocks -> 2 per CU
  dim3 block(256);
  lstm_stag<<<grid, block, 0, stream>>>(x, w_ih, w_hh, b_ih, b_hh, w_lin,
                                        b_lin, out);
}

// Round 16
// 88.180 us; speedup vs baseline: 1.5073x; 1.0557x over previous
//
#include <hip/hip_runtime.h>

// Fused LSTM B=16384, T=60, IN=1, H=50, OUT=1 — R10 + phase-split nonlin.
// (R15 resubmit: FIXED the P3/P4 swap in Stage C — so = r34*P4 = sigmoid(o),
// tg = 1-2*r34*P3 = tanh(g); R15 had them crossed -> absmax 0.57.)
// 512 blocks x 256 thr (4 waves, 2 blk/CU). Dual 16-batch groups, 13 tiles
// {4,4,4,1}, identity k-map, bias k=62, x k=63, H fp16 swizzled dbuf.
// Theory: R10's per-slot nonlin chain (~200 cyc dependent) was compiler-
// serialized across slots (VGPR 52). Phase-split into 5 stages over ALL
// slots (exps | P+rcp | gates+c | tanh-exps | finish+write) holds stage
// state in register arrays -> producer/consumer distance = a full stage.

namespace {
constexpr int TS = 60;

typedef _Float16 half8 __attribute__((ext_vector_type(8)));
typedef _Float16 half2v __attribute__((ext_vector_type(2)));
typedef float f32x4 __attribute__((ext_vector_type(4)));

__device__ __forceinline__ float fexp2(float x) { return __builtin_amdgcn_exp2f(x); }
__device__ __forceinline__ float frcp(float x) { return __builtin_amdgcn_rcpf(x); }
__device__ __forceinline__ f32x4 mfma16(half8 a, half8 b, f32x4 c) {
  return __builtin_amdgcn_mfma_f32_16x16x32_f16(a, b, c, 0, 0, 0);
}
}  // namespace

__global__ __launch_bounds__(256, 2) void lstm_ph(
    const float* __restrict__ x,      // [B][60]
    const float* __restrict__ w_ih,   // [200]
    const float* __restrict__ w_hh,   // [200][50]
    const float* __restrict__ b_ih,   // [200]
    const float* __restrict__ b_hh,   // [200]
    const float* __restrict__ w_lin,  // [3000]
    const float* __restrict__ b_lin,  // [1]
    float* __restrict__ out)          // [B]
{
  __shared__ __align__(16) _Float16 Hs[2][2][16 * 64];  // [grp][buf] 8 KB
  __shared__ float WL[TS * 64];   // 15.36 KB [t][u], 0-padded
  __shared__ float XL[TS * 32];   // 7.68 KB [t][b]
  __shared__ float OB[4][2][16];  // 512 B

  const int tid = threadIdx.x;
  const int lane = tid & 63;
  const int wv = tid >> 6;   // 0..3
  const int g = lane >> 4;   // lane quad-group: B k-owner, D row-block (du)
  const int cl = lane & 15;  // batch-in-group; A/B/D column
  const int s8 = cl & 7;
  const long bbase = (long)blockIdx.x * 32;

  // ---- stage XL[t][b] ----
  for (int i = tid; i < TS * 32; i += 256) {
    const int b = i / TS, t = i - b * TS;
    XL[t * 32 + b] = x[bbase * TS + i];
  }
  // ---- stage WL[t][u] ----
  for (int i = tid; i < TS * 64; i += 256) {
    const int t = i >> 6, u = i & 63;
    WL[i] = (u < 50) ? w_lin[t * 50 + u] : 0.0f;
  }
  // ---- zero all H buffers (h0 = 0; pad k-slots stay 0 forever) ----
  for (int i = tid; i < 2048; i += 256) ((unsigned*)Hs)[i] = 0u;

  // ---- gather this wave's A-fragments (fp32 -> fp16), once ----
  half8 A[4][2];
  {
    const int gate = cl & 3, du = cl >> 2;
    const int ntile = (wv < 3) ? 4 : 1;
#pragma unroll
    for (int tau = 0; tau < 4; ++tau) {
      const int T = (wv < 3) ? (4 * wv + tau) : 12;
      const int uA = 4 * T + du;
      const int orig = gate * 50 + uA;
      const bool valid = (tau < ntile) && (uA < 50);
#pragma unroll
      for (int kc = 0; kc < 2; ++kc) {
        half8 fr;
#pragma unroll
        for (int e = 0; e < 8; ++e) {
          const int k = kc * 32 + 8 * g + e;
          float v = 0.0f;
          if (valid) {
            if (k < 50) v = w_hh[orig * 50 + k];
            else if (k == 62) v = b_ih[orig] + b_hh[orig];
            else if (k == 63) v = w_ih[orig];
          }
          fr[e] = (_Float16)v;
        }
        A[tau][kc] = fr;
      }
    }
  }
  __syncthreads();

  // ---- specials in buf0 (both groups): k=62 -> 1.0, k=63 -> x_0 ----
  if (wv == 3 && g == 3) {
#pragma unroll
    for (int grp = 0; grp < 2; ++grp) {
      const half2v sp = {(_Float16)1.0f, (_Float16)XL[grp * 16 + cl]};
      *(half2v*)&Hs[grp][0][cl * 64 + ((7 ^ s8) << 3) + 6] = sp;
    }
  }
  __syncthreads();

  // B-frag read offsets (halves): kc0 -> chunk g, kc1 -> chunk 4+g
  const int rh0 = cl * 64 + ((g ^ s8) << 3);
  const int rh1 = cl * 64 + (((4 | g) ^ s8) << 3);

  float c[2][4] = {{0.f, 0.f, 0.f, 0.f}, {0.f, 0.f, 0.f, 0.f}};
  float oacc[2] = {0.f, 0.f};

  constexpr float L1 = 1.4426950408889634f;  // log2(e)
  constexpr float L2 = 2.8853900817779268f;  // 2*log2(e)

#define DO_TILES(NT, TBASE)                                                   \
  {                                                                           \
    f32x4 acc[2][NT];                                                         \
    _Pragma("unroll") for (int grp = 0; grp < 2; ++grp) {                     \
      _Pragma("unroll") for (int tau = 0; tau < NT; ++tau) {                  \
        f32x4 a = {0.f, 0.f, 0.f, 0.f};                                       \
        a = mfma16(A[tau][0], grp ? B0b : B0a, a);                            \
        a = mfma16(A[tau][1], grp ? B1b : B1a, a);                            \
        acc[grp][tau] = a;                                                    \
      }                                                                       \
    }                                                                         \
    float wlv[NT];                                                            \
    _Pragma("unroll") for (int tau = 0; tau < NT; ++tau)                      \
        wlv[tau] = WL[t * 64 + 4 * (TBASE + tau) + g];                        \
    /* ---- Stage A: ALL gate exps (independent, trans-pipe pipelined) ---- */\
    float E[2][NT][4];                                                        \
    _Pragma("unroll") for (int grp = 0; grp < 2; ++grp)                       \
    _Pragma("unroll") for (int tau = 0; tau < NT; ++tau) {                    \
      E[grp][tau][0] = fexp2(-L1 * acc[grp][tau][0]);                         \
      E[grp][tau][1] = fexp2(-L1 * acc[grp][tau][1]);                         \
      E[grp][tau][2] = fexp2(L2 * acc[grp][tau][2]);                          \
      E[grp][tau][3] = fexp2(-L1 * acc[grp][tau][3]);                         \
    }                                                                         \
    /* ---- Stage B: ALL P sums, pair products, batched rcps ---- */          \
    float P1[2][NT], P2[2][NT], P3[2][NT], P4[2][NT];                         \
    float q12[2][NT], q34[2][NT], r[2][NT];                                   \
    _Pragma("unroll") for (int grp = 0; grp < 2; ++grp)                       \
    _Pragma("unroll") for (int tau = 0; tau < NT; ++tau) {                    \
      P1[grp][tau] = 1.0f + E[grp][tau][0];                                   \
      P2[grp][tau] = 1.0f + E[grp][tau][1];                                   \
      P4[grp][tau] = 1.0f + E[grp][tau][2];                                   \
      P3[grp][tau] = 1.0f + E[grp][tau][3];                                   \
      q12[grp][tau] = P1[grp][tau] * P2[grp][tau];                            \
      q34[grp][tau] = P3[grp][tau] * P4[grp][tau];                            \
      r[grp][tau] = frcp(q12[grp][tau] * q34[grp][tau]);                      \
    }                                                                         \
    /* ---- Stage C: ALL gate combines + c updates (R10 algebra) ---- */      \
    float so[2][NT], cn[2][NT];                                               \
    _Pragma("unroll") for (int grp = 0; grp < 2; ++grp)                       \
    _Pragma("unroll") for (int tau = 0; tau < NT; ++tau) {                    \
      const float r12 = r[grp][tau] * q34[grp][tau];                          \
      const float r34 = r[grp][tau] * q12[grp][tau];                          \
      const float si = r12 * P2[grp][tau];  /* 1/P1 = sigm(i) */              \
      const float sf = r12 * P1[grp][tau];  /* 1/P2 = sigm(f) */              \
      so[grp][tau] = r34 * P4[grp][tau];    /* 1/P3 = sigm(o) — FIXED */      \
      const float tg = fmaf(-2.0f, r34 * P3[grp][tau], 1.0f); /* tanh(g) */   \
      cn[grp][tau] = fmaf(sf, c[grp][tau], si * tg);                          \
      c[grp][tau] = cn[grp][tau];                                             \
    }                                                                         \
    /* ---- Stage D: ALL tanh exps ---- */                                    \
    float Ec[2][NT];                                                          \
    _Pragma("unroll") for (int grp = 0; grp < 2; ++grp)                       \
    _Pragma("unroll") for (int tau = 0; tau < NT; ++tau)                      \
      Ec[grp][tau] = fexp2(L2 * cn[grp][tau]);                                \
    /* ---- Stage E: ALL finishes + writes ---- */                            \
    _Pragma("unroll") for (int grp = 0; grp < 2; ++grp)                       \
    _Pragma("unroll") for (int tau = 0; tau < NT; ++tau) {                    \
      const float tc = fmaf(-2.0f, frcp(1.0f + Ec[grp][tau]), 1.0f);          \
      const float hn = so[grp][tau] * tc;                                     \
      oacc[grp] = fmaf(hn, wlv[tau], oacc[grp]);                              \
      const int u = 4 * (TBASE + tau) + g;                                    \
      const int widx = cl * 64 + (((u >> 3) ^ s8) << 3) + (u & 7);            \
      (grp ? HN1 : HN0)[widx] = (_Float16)hn;                                 \
    }                                                                         \
  }

#pragma unroll 1
  for (int t = 0; t < TS; ++t) {
    const int p = t & 1;
    const _Float16* HR0 = &Hs[0][p][0];
    const _Float16* HR1 = &Hs[1][p][0];
    _Float16* HN0 = &Hs[0][p ^ 1][0];
    _Float16* HN1 = &Hs[1][p ^ 1][0];
    const half8 B0a = *(const half8*)&HR0[rh0];
    const half8 B1a = *(const half8*)&HR0[rh1];
    const half8 B0b = *(const half8*)&HR1[rh0];
    const half8 B1b = *(const half8*)&HR1[rh1];

    if (wv < 3) {
      const int tb = 4 * wv;
      DO_TILES(4, tb);
    } else {
      DO_TILES(1, 12);
      if (g == 3) {  // specials for next step: k=62 -> 1.0, k=63 -> x_{t+1}
        const int tn = (t + 1 < TS) ? (t + 1) : (TS - 1);
        const half2v spa = {(_Float16)1.0f, (_Float16)XL[tn * 32 + cl]};
        const half2v spb = {(_Float16)1.0f, (_Float16)XL[tn * 32 + 16 + cl]};
        *(half2v*)&HN0[cl * 64 + ((7 ^ s8) << 3) + 6] = spa;
        *(half2v*)&HN1[cl * 64 + ((7 ^ s8) << 3) + 6] = spb;
      }
    }
    __syncthreads();
  }
#undef DO_TILES

  // ---- reduce over g (shfl), then over waves (LDS) ----
  oacc[0] += __shfl_xor(oacc[0], 32);
  oacc[0] += __shfl_xor(oacc[0], 16);
  oacc[1] += __shfl_xor(oacc[1], 32);
  oacc[1] += __shfl_xor(oacc[1], 16);
  if (lane < 16) {
    OB[wv][0][cl] = oacc[0];
    OB[wv][1][cl] = oacc[1];
  }
  __syncthreads();
  if (tid < 32) {
    const int grp = tid >> 4, b = tid & 15;
    float s = b_lin[0];
#pragma unroll
    for (int q = 0; q < 4; ++q) s += OB[q][grp][b];
    out[bbase + grp * 16 + b] = s;
  }
}

extern "C" void kernel_launch(void* const* d_in, const int* in_sizes, int n_in,
                              void* d_out, int out_size, void* d_ws, size_t ws_size,
                              hipStream_t stream) {
  const float* x     = (const float*)d_in[0];
  const float* w_ih  = (const float*)d_in[1];
  const float* w_hh  = (const float*)d_in[2];
  const float* b_ih  = (const float*)d_in[3];
  const float* b_hh  = (const float*)d_in[4];
  const float* w_lin = (const float*)d_in[5];
  const float* b_lin = (const float*)d_in[6];
  float* out = (float*)d_out;

  dim3 grid(16384 / 32);  // 512 blocks -> 2 per CU
  dim3 block(256);
  lstm_ph<<<grid, block, 0, stream>>>(x, w_ih, w_hh, b_ih, b_hh, w_lin,
                                      b_lin, out);
}